// Round 5
// baseline (230.978 us; speedup 1.0000x reference)
//
#include <hip/hip_runtime.h>
#include <hip/hip_bf16.h>

typedef unsigned short ushort_t;
typedef unsigned int uint_t;
using f32x4  = __attribute__((ext_vector_type(4))) float;
using short8 = __attribute__((ext_vector_type(8))) short;

#define NN 8192

__device__ __forceinline__ ushort_t f2bf(float f) {
  uint_t u = __builtin_bit_cast(uint_t, f);
  u += 0x7FFFu + ((u >> 16) & 1u);   // RNE
  return (ushort_t)(u >> 16);
}

// ---------------------------------------------------------------------------
// K1: Xp = X @ W  -> XpT bf16 [2*64][8192] (row = h*64+c), x0[N][2], x1T[2][N]
// ---------------------------------------------------------------------------
__global__ __launch_bounds__(256, 2) void k1_project(
    const float* __restrict__ X, const float* __restrict__ W,
    const float* __restrict__ attn,
    ushort_t* __restrict__ XpT, float* __restrict__ x0g, float* __restrict__ x1g)
{
  __shared__ float    Xl[32][128];      // 16 KB
  __shared__ ushort_t XpL[128][56];     // 14 KB
  __shared__ float    P0[128][33];
  __shared__ float    P1[128][33];
  const int t  = threadIdx.x;
  const int nb = blockIdx.x * 32;

  #pragma unroll
  for (int r = 0; r < 4; ++r) {
    int chunk = r * 256 + t;
    ((float4*)(&Xl[0][0]))[chunk] = ((const float4*)(X + (size_t)nb * 128))[chunk];
  }
  __syncthreads();

  const int p = t & 127;
  const int g = t >> 7;
  const int h = p & 1, c = p >> 1;

  float acc[16];
  #pragma unroll
  for (int n = 0; n < 16; ++n) acc[n] = 0.f;

  for (int jc = 0; jc < 4; ++jc) {
    float wreg[32];
    #pragma unroll
    for (int jj = 0; jj < 32; ++jj) wreg[jj] = W[(jc * 32 + jj) * 128 + p];
    #pragma unroll
    for (int n = 0; n < 16; ++n) {
      const float4* xr = (const float4*)(&Xl[g * 16 + n][jc * 32]);
      float s = acc[n];
      #pragma unroll
      for (int q = 0; q < 8; ++q) {
        float4 xv = xr[q];
        s += xv.x * wreg[q*4+0] + xv.y * wreg[q*4+1] + xv.z * wreg[q*4+2] + xv.w * wreg[q*4+3];
      }
      acc[n] = s;
    }
  }

  const float a0 = attn[p];
  const float a1 = attn[128 + p];
  const int   row = h * 64 + c;
  #pragma unroll
  for (int n = 0; n < 16; ++n) {
    P0[p][g * 16 + n]  = acc[n] * a0;
    P1[p][g * 16 + n]  = acc[n] * a1;
    XpL[row][g * 16 + n] = f2bf(acc[n]);
  }
  __syncthreads();

  if (t < 128) {
    ushort_t* dst = XpT + (size_t)t * NN + nb;
    const uint4* src = (const uint4*)(&XpL[t][0]);
    ((uint4*)dst)[0] = src[0];
    ((uint4*)dst)[1] = src[1];
    ((uint4*)dst)[2] = src[2];
    ((uint4*)dst)[3] = src[3];
  }
  if (t < 64) {
    int node = t >> 1, hh = t & 1;
    float s0 = 0.f, s1 = 0.f;
    #pragma unroll
    for (int cc = 0; cc < 64; ++cc) {
      s0 += P0[cc * 2 + hh][node];
      s1 += P1[cc * 2 + hh][node];
    }
    x0g[(nb + node) * 2 + hh] = s0;
    x1g[hh * NN + nb + node]  = s1;
  }
}

// ---------------------------------------------------------------------------
// K2: barrier-free, LDS-free. Each lane loads A in MFMA-A-fragment layout
// (row=lane&15, k=(lane>>4)*8..+7), computes P in-register (that IS the
// A-frag), MFMAs against B-frags JIT-prefetched from L2-resident XpT.
// 4 waves/block: head=w&1, row-half=w>>1 (BI=32). acc[4] covers 64 channels.
// S=8 k-splits: blocks with split sp land on XCD sp -> per-XCD L2 locality.
// ---------------------------------------------------------------------------
__global__ __launch_bounds__(256, 4) void k2_main(
    const float* __restrict__ A, const ushort_t* __restrict__ XpT,
    const float* __restrict__ x0g, const float* __restrict__ x1g,
    float* __restrict__ part, float* __restrict__ denp,
    const int S, const int KS)
{
  const int t  = threadIdx.x;
  const int b  = blockIdx.x;
  const int rb = b / S, sp = b % S;
  const int ib = rb * 32;
  const int k0 = sp * KS;
  const int lane = t & 63, w = t >> 6;
  const int hw = w & 1;                 // head
  const int rh = w >> 1;                // row-half
  const int row = ib + rh * 16 + (lane & 15);
  const int kl  = (lane >> 4) * 8;      // k offset within 32-step

  const float x0s = x0g[row * 2 + hw];

  const float*    Ap = A   + (size_t)row * NN + k0 + kl;
  const float*    Xq = x1g + (size_t)hw  * NN + k0 + kl;
  const ushort_t* Bp[4];
  #pragma unroll
  for (int cb = 0; cb < 4; ++cb)
    Bp[cb] = XpT + (size_t)(hw * 64 + cb * 16 + (lane & 15)) * NN + k0 + kl;

  f32x4 acc[4] = {};
  float den = 0.f;
  const int nt = KS >> 5;

  // prologue: fragment loads for tile 0
  float4 aC0 = *(const float4*)(Ap);
  float4 aC1 = *(const float4*)(Ap + 4);
  short8 bC[4];
  #pragma unroll
  for (int cb = 0; cb < 4; ++cb) bC[cb] = *(const short8*)(Bp[cb]);

  for (int tt = 0; tt < nt; ++tt) {
    const bool pf = (tt + 1 < nt);
    const int  kn = (tt + 1) << 5;

    // 1-deep register prefetch (no barriers -> freely hoisted/overlapped)
    float4 aN0, aN1; short8 bN[4];
    if (pf) {
      aN0 = *(const float4*)(Ap + kn);
      aN1 = *(const float4*)(Ap + kn + 4);
      #pragma unroll
      for (int cb = 0; cb < 4; ++cb) bN[cb] = *(const short8*)(Bp[cb] + kn);
    }

    // x1: JIT (L1-hot broadcast: 16 lanes share each address)
    float4 xv0 = *(const float4*)(Xq + (tt << 5));
    float4 xv1 = *(const float4*)(Xq + (tt << 5) + 4);

    // ---- P compute: 8 values, in MFMA A-frag layout ----
    float av[8] = {aC0.x, aC0.y, aC0.z, aC0.w, aC1.x, aC1.y, aC1.z, aC1.w};
    float xv[8] = {xv0.x, xv0.y, xv0.z, xv0.w, xv1.x, xv1.y, xv1.z, xv1.w};
    float p[8];
    #pragma unroll
    for (int j = 0; j < 8; ++j) {
      float s = x0s + xv[j];
      float e = __expf(fmaxf(s, 0.2f * s));
      p[j] = av[j] * e;
      den += p[j];
    }
    uint_t u0, u1, u2, u3;
    asm("v_cvt_pk_bf16_f32 %0, %1, %2" : "=v"(u0) : "v"(p[0]), "v"(p[1]));
    asm("v_cvt_pk_bf16_f32 %0, %1, %2" : "=v"(u1) : "v"(p[2]), "v"(p[3]));
    asm("v_cvt_pk_bf16_f32 %0, %1, %2" : "=v"(u2) : "v"(p[4]), "v"(p[5]));
    asm("v_cvt_pk_bf16_f32 %0, %1, %2" : "=v"(u3) : "v"(p[6]), "v"(p[7]));
    uint4 uv; uv.x = u0; uv.y = u1; uv.z = u2; uv.w = u3;
    short8 af = __builtin_bit_cast(short8, uv);

    #pragma unroll
    for (int cb = 0; cb < 4; ++cb)
      acc[cb] = __builtin_amdgcn_mfma_f32_16x16x32_bf16(af, bC[cb], acc[cb], 0, 0, 0);

    if (pf) {
      aC0 = aN0; aC1 = aN1;
      #pragma unroll
      for (int cb = 0; cb < 4; ++cb) bC[cb] = bN[cb];
    }
  }

  // den: combine the 4 k-groups (lanes xor 16, 32 hold same row)
  den += __shfl_xor(den, 16);
  den += __shfl_xor(den, 32);
  if (lane < 16)
    denp[((size_t)sp * NN + ib + rh * 16 + lane) * 2 + hw] = den;

  // partial numerators (C/D layout: col=lane&15, row=(lane>>4)*4+r)
  float* pbase = part + ((size_t)sp * NN + ib + rh * 16) * 128;
  #pragma unroll
  for (int cb = 0; cb < 4; ++cb) {
    #pragma unroll
    for (int r = 0; r < 4; ++r) {
      int lr  = (lane >> 4) * 4 + r;
      int col = cb * 16 + (lane & 15);
      pbase[lr * 128 + hw * 64 + col] = acc[cb][r];
    }
  }
}

// ---------------------------------------------------------------------------
// K3: combine splits, normalize, add bias.
// ---------------------------------------------------------------------------
__global__ __launch_bounds__(256) void k3_finish(
    const float* __restrict__ part, const float* __restrict__ denp,
    const float* __restrict__ bias, float* __restrict__ out, const int S)
{
  const int idx = blockIdx.x * 256 + threadIdx.x;
  const int i  = idx >> 5;
  const int hc = (idx & 31) * 4;
  const int h  = hc >> 6;
  float4 s; s.x = s.y = s.z = s.w = 0.f;
  float d = 0.f;
  for (int sp = 0; sp < S; ++sp) {
    float4 v = *(const float4*)(part + ((size_t)sp * NN + i) * 128 + hc);
    s.x += v.x; s.y += v.y; s.z += v.z; s.w += v.w;
    d += denp[((size_t)sp * NN + i) * 2 + h];
  }
  const float sc = 1.f / (d + 0.001f);
  float4 bv = *(const float4*)(bias + hc);
  float4 o;
  o.x = s.x * sc + bv.x;
  o.y = s.y * sc + bv.y;
  o.z = s.z * sc + bv.z;
  o.w = s.w * sc + bv.w;
  *(float4*)(out + (size_t)i * 128 + hc) = o;
}

extern "C" void kernel_launch(void* const* d_in, const int* in_sizes, int n_in,
                              void* d_out, int out_size, void* d_ws, size_t ws_size,
                              hipStream_t stream) {
  const float* A    = (const float*)d_in[0];
  const float* X    = (const float*)d_in[1];
  const float* W    = (const float*)d_in[2];
  const float* attn = (const float*)d_in[3];
  const float* bias = (const float*)d_in[4];
  float* out = (float*)d_out;

  char* ws = (char*)d_ws;
  size_t off = 0;
  ushort_t* XpT = (ushort_t*)(ws + off); off += (size_t)128 * NN * sizeof(ushort_t);
  float* x0g = (float*)(ws + off); off += (size_t)NN * 2 * sizeof(float);
  float* x1g = (float*)(ws + off); off += (size_t)2 * NN * sizeof(float);

  int S = 8;   // 8 k-splits: split sp -> XCD sp (b%8), per-XCD L2 locality
  while (S > 1) {
    size_t need = off + (size_t)S * NN * 2 * 4 + (size_t)S * NN * 128 * 4;
    if (need <= ws_size) break;
    S >>= 1;
  }
  float* denp = (float*)(ws + off); off += (size_t)S * NN * 2 * sizeof(float);
  float* part = (float*)(ws + off);
  const int KS = NN / S;

  k1_project<<<256, 256, 0, stream>>>(X, W, attn, XpT, x0g, x1g);
  k2_main<<<(NN / 32) * S, 256, 0, stream>>>(A, XpT, x0g, x1g, part, denp, S, KS);
  k3_finish<<<1024, 256, 0, stream>>>(part, denp, bias, out, S);
}

// Round 7
// 119.682 us; speedup vs baseline: 1.9299x; 1.9299x over previous
//
#include <hip/hip_runtime.h>
#include <hip/hip_bf16.h>

typedef unsigned short ushort_t;
typedef unsigned int uint_t;
using f32x4  = __attribute__((ext_vector_type(4))) float;
using short8 = __attribute__((ext_vector_type(8))) short;

#define NN 8192

__device__ __forceinline__ ushort_t f2bf(float f) {
  uint_t u = __builtin_bit_cast(uint_t, f);
  u += 0x7FFFu + ((u >> 16) & 1u);   // RNE
  return (ushort_t)(u >> 16);
}

__device__ __forceinline__ void gload16(const void* g, void* l) {
  __builtin_amdgcn_global_load_lds(
      (const __attribute__((address_space(1))) void*)g,
      (__attribute__((address_space(3))) void*)l, 16, 0, 0);
}

// ---------------------------------------------------------------------------
// K1: Xp = X @ W  -> XpT bf16 [2*64][8192] (row = h*64+c), x0[N][2], x1T[2][N]
// ---------------------------------------------------------------------------
__global__ __launch_bounds__(256, 2) void k1_project(
    const float* __restrict__ X, const float* __restrict__ W,
    const float* __restrict__ attn,
    ushort_t* __restrict__ XpT, float* __restrict__ x0g, float* __restrict__ x1g)
{
  __shared__ float    Xl[32][128];      // 16 KB
  __shared__ ushort_t XpL[128][56];     // 14 KB
  __shared__ float    P0[128][33];
  __shared__ float    P1[128][33];
  const int t  = threadIdx.x;
  const int nb = blockIdx.x * 32;

  #pragma unroll
  for (int r = 0; r < 4; ++r) {
    int chunk = r * 256 + t;
    ((float4*)(&Xl[0][0]))[chunk] = ((const float4*)(X + (size_t)nb * 128))[chunk];
  }
  __syncthreads();

  const int p = t & 127;
  const int g = t >> 7;
  const int h = p & 1, c = p >> 1;

  float acc[16];
  #pragma unroll
  for (int n = 0; n < 16; ++n) acc[n] = 0.f;

  for (int jc = 0; jc < 4; ++jc) {
    float wreg[32];
    #pragma unroll
    for (int jj = 0; jj < 32; ++jj) wreg[jj] = W[(jc * 32 + jj) * 128 + p];
    #pragma unroll
    for (int n = 0; n < 16; ++n) {
      const float4* xr = (const float4*)(&Xl[g * 16 + n][jc * 32]);
      float s = acc[n];
      #pragma unroll
      for (int q = 0; q < 8; ++q) {
        float4 xv = xr[q];
        s += xv.x * wreg[q*4+0] + xv.y * wreg[q*4+1] + xv.z * wreg[q*4+2] + xv.w * wreg[q*4+3];
      }
      acc[n] = s;
    }
  }

  const float a0 = attn[p];
  const float a1 = attn[128 + p];
  const int   row = h * 64 + c;
  #pragma unroll
  for (int n = 0; n < 16; ++n) {
    P0[p][g * 16 + n]  = acc[n] * a0;
    P1[p][g * 16 + n]  = acc[n] * a1;
    XpL[row][g * 16 + n] = f2bf(acc[n]);
  }
  __syncthreads();

  if (t < 128) {
    ushort_t* dst = XpT + (size_t)t * NN + nb;
    const uint4* src = (const uint4*)(&XpL[t][0]);
    ((uint4*)dst)[0] = src[0];
    ((uint4*)dst)[1] = src[1];
    ((uint4*)dst)[2] = src[2];
    ((uint4*)dst)[3] = src[3];
  }
  if (t < 64) {
    int node = t >> 1, hh = t & 1;
    float s0 = 0.f, s1 = 0.f;
    #pragma unroll
    for (int cc = 0; cc < 64; ++cc) {
      s0 += P0[cc * 2 + hh][node];
      s1 += P1[cc * 2 + hh][node];
    }
    x0g[(nb + node) * 2 + hh] = s0;
    x1g[hh * NN + nb + node]  = s1;
  }
}

// ---------------------------------------------------------------------------
// K2: round-3 structure (verified) + 2-deep A/x1 register prefetch (unroll-2,
// two NAMED reg sets; refills issued inside the barrier-sandwiched zone so
// the "memory" clobbers pin them). B staged via global_load_lds into
// double-buffered LDS; counted vmcnt(8) at barrier B (re-derived: 8 vmem
// issued per body -> vmcnt(8) guarantees B(t) staged and A-set(t+1) done).
// ---------------------------------------------------------------------------
__global__ __launch_bounds__(256, 4) void k2_main(
    const float* __restrict__ A, const ushort_t* __restrict__ XpT,
    const float* __restrict__ x0g, const float* __restrict__ x1g,
    float* __restrict__ part, float* __restrict__ denp,
    const int S, const int KS)
{
  __shared__ __align__(16) ushort_t Pl[64 * 64];        // 8 KB single
  __shared__ __align__(16) ushort_t Bl[2 * 128 * 64];   // 32 KB double buffer
  const int t  = threadIdx.x;
  const int b  = blockIdx.x;
  const int rb = b / S, sp = b % S;
  const int ib = rb * 32;
  const int k0 = sp * KS;
  const int lane = t & 63, w = t >> 6;
  const int hw = w & 1, iw = (w >> 1) * 16;
  const int pr = t >> 4;
  const int pk = (t & 15) * 4;

  float x0a[2][2];
  #pragma unroll
  for (int ps = 0; ps < 2; ++ps) {
    float2 v = *(const float2*)(x0g + (ib + ps * 16 + pr) * 2);
    x0a[ps][0] = v.x; x0a[ps][1] = v.y;
  }

  // B-stage addressing: chunk c = q*256+t -> LDS linear c*16B; source granule
  // inverse-swizzled so swizzled reads (byte ^ ((row&7)<<4)) see linear data.
  int srcOff[4], ldsOff[4];
  #pragma unroll
  for (int q = 0; q < 4; ++q) {
    int c = q * 256 + t;
    int cr = c >> 3, j = c & 7;
    srcOff[q] = cr * NN + ((j ^ (cr & 7)) << 3);  // elements
    ldsOff[q] = (q * 256 + w * 64) << 3;          // elements, wave-uniform
  }

  // Pl write byte offsets
  int plw[2][2];
  #pragma unroll
  for (int ps = 0; ps < 2; ++ps)
    #pragma unroll
    for (int hh = 0; hh < 2; ++hh) {
      int row = hh * 32 + ps * 16 + pr;
      plw[ps][hh] = (row * 128 + pk * 2) ^ ((pr & 7) << 4);
    }

  // MFMA read byte offsets
  int aoff[2], boff[2][4];
  const int arow = hw * 32 + iw + (lane & 15);
  #pragma unroll
  for (int ks = 0; ks < 2; ++ks) {
    aoff[ks] = (arow * 128 + ks * 64 + (lane >> 4) * 16) ^ ((arow & 7) << 4);
    #pragma unroll
    for (int cb = 0; cb < 4; ++cb) {
      int brow = hw * 64 + cb * 16 + (lane & 15);
      boff[ks][cb] = (brow * 128 + ks * 64 + (lane >> 4) * 16) ^ ((brow & 7) << 4);
    }
  }

  f32x4 acc[4] = {};
  float den[2][2] = {};

  const float* Ap0 = A + (size_t)(ib + pr) * NN + k0 + pk;
  const float* Ap1 = A + (size_t)(ib + 16 + pr) * NN + k0 + pk;
  const float* Xq0 = x1g + k0 + pk;
  const float* Xq1 = x1g + NN + k0 + pk;
  const int nt = KS >> 6;               // 32 for S=4 (always even)
  const int lastT = nt - 1;

  // --- prologue: A/x1 sets for tiles 0 (U) and 1 (V); stage B(0) ---
  float4 Ua0 = *(const float4*)(Ap0);
  float4 Ua1 = *(const float4*)(Ap1);
  float4 Ux0 = *(const float4*)(Xq0);
  float4 Ux1 = *(const float4*)(Xq1);
  float4 Va0 = *(const float4*)(Ap0 + 64);
  float4 Va1 = *(const float4*)(Ap1 + 64);
  float4 Vx0 = *(const float4*)(Xq0 + 64);
  float4 Vx1 = *(const float4*)(Xq1 + 64);
  {
    const ushort_t* s = XpT + k0;
    #pragma unroll
    for (int q = 0; q < 4; ++q) gload16(s + srcOff[q], Bl + ldsOff[q]);
  }

#define KBODY(a0v, a1v, x0v, x1v, TT, PAR)                                   \
  {                                                                          \
    const int  t_  = (TT);                                                   \
    const bool pf_ = (t_ + 1 < nt);                                          \
    /* ---- P compute from this body's reg set ---- */                       \
    float aarr[2][4] = {{a0v.x, a0v.y, a0v.z, a0v.w},                        \
                        {a1v.x, a1v.y, a1v.z, a1v.w}};                       \
    float xarr[2][4] = {{x0v.x, x0v.y, x0v.z, x0v.w},                        \
                        {x1v.x, x1v.y, x1v.z, x1v.w}};                       \
    uint_t pp[2][2][2];                                                      \
    _Pragma("unroll")                                                        \
    for (int ps = 0; ps < 2; ++ps) {                                         \
      _Pragma("unroll")                                                      \
      for (int hh = 0; hh < 2; ++hh) {                                       \
        ushort_t bfv[4];                                                     \
        _Pragma("unroll")                                                    \
        for (int j = 0; j < 4; ++j) {                                        \
          float s   = x0a[ps][hh] + xarr[hh][j];                             \
          float lrl = fmaxf(s, 0.2f * s);                                    \
          float e   = __expf(lrl);                                           \
          float pv  = aarr[ps][j] * e;                                       \
          den[ps][hh] += pv;                                                 \
          bfv[j] = f2bf(pv);                                                 \
        }                                                                    \
        pp[ps][hh][0] = (uint_t)bfv[0] | ((uint_t)bfv[1] << 16);             \
        pp[ps][hh][1] = (uint_t)bfv[2] | ((uint_t)bfv[3] << 16);             \
      }                                                                      \
    }                                                                        \
    /* ---- barrier A: all waves done reading Pl(prev) & Bl[PAR^1] ---- */   \
    asm volatile("s_waitcnt lgkmcnt(0)" ::: "memory");                       \
    __builtin_amdgcn_s_barrier();                                            \
    asm volatile("" ::: "memory");                                           \
    /* stage B(t+1) into the buffer MFMA(t) does not read */                 \
    if (pf_) {                                                               \
      const ushort_t* s_ = XpT + k0 + ((t_ + 1) << 6);                       \
      ushort_t* d_ = Bl + ((PAR) ^ 1) * 8192;                                \
      _Pragma("unroll")                                                      \
      for (int q = 0; q < 4; ++q) gload16(s_ + srcOff[q], d_ + ldsOff[q]);   \
    }                                                                        \
    /* refill this set with tile t+2 (clamped; redundant tail loads ok) */   \
    {                                                                        \
      const int rt_ = (t_ + 2 < nt) ? (t_ + 2) : lastT;                      \
      const int rk_ = rt_ << 6;                                              \
      a0v = *(const float4*)(Ap0 + rk_);                                     \
      a1v = *(const float4*)(Ap1 + rk_);                                     \
      x0v = *(const float4*)(Xq0 + rk_);                                     \
      x1v = *(const float4*)(Xq1 + rk_);                                     \
    }                                                                        \
    /* write Pl(t) */                                                        \
    _Pragma("unroll")                                                        \
    for (int ps = 0; ps < 2; ++ps) {                                         \
      _Pragma("unroll")                                                      \
      for (int hh = 0; hh < 2; ++hh) {                                       \
        uint2 v_; v_.x = pp[ps][hh][0]; v_.y = pp[ps][hh][1];                \
        *(uint2*)((char*)Pl + plw[ps][hh]) = v_;                             \
      }                                                                      \
    }                                                                        \
    /* ---- barrier B: Pl(t) written; B(t) staged (counted vmcnt) ---- */    \
    if (pf_) asm volatile("s_waitcnt vmcnt(8) lgkmcnt(0)" ::: "memory");     \
    else     asm volatile("s_waitcnt vmcnt(0) lgkmcnt(0)" ::: "memory");     \
    __builtin_amdgcn_s_barrier();                                            \
    asm volatile("" ::: "memory");                                           \
    /* ---- MFMA on tile t ---- */                                           \
    const char* BlC_ = (const char*)(Bl + (PAR) * 8192);                     \
    _Pragma("unroll")                                                        \
    for (int ks = 0; ks < 2; ++ks) {                                         \
      short8 af = *(const short8*)((const char*)Pl + aoff[ks]);              \
      _Pragma("unroll")                                                      \
      for (int cb = 0; cb < 4; ++cb) {                                       \
        short8 bv = *(const short8*)(BlC_ + boff[ks][cb]);                   \
        acc[cb] = __builtin_amdgcn_mfma_f32_16x16x32_bf16(af, bv, acc[cb], 0, 0, 0); \
      }                                                                      \
    }                                                                        \
  }

  for (int tt = 0; tt < nt; tt += 2) {
    KBODY(Ua0, Ua1, Ux0, Ux1, tt,     0)
    KBODY(Va0, Va1, Vx0, Vx1, tt + 1, 1)
  }
#undef KBODY

  // --- den: reduce across 16-lane groups ---
  #pragma unroll
  for (int ps = 0; ps < 2; ++ps) {
    #pragma unroll
    for (int hh = 0; hh < 2; ++hh) {
      float d = den[ps][hh];
      d += __shfl_xor(d, 1, 16);
      d += __shfl_xor(d, 2, 16);
      d += __shfl_xor(d, 4, 16);
      d += __shfl_xor(d, 8, 16);
      if ((t & 15) == 0)
        denp[((size_t)sp * NN + ib + ps * 16 + (t >> 4)) * 2 + hh] = d;
    }
  }

  // --- partial numerators (C/D layout: col=lane&15, row=(lane>>4)*4+r) ---
  float* pbase = part + ((size_t)sp * NN + ib) * 128;
  #pragma unroll
  for (int cb = 0; cb < 4; ++cb) {
    #pragma unroll
    for (int r = 0; r < 4; ++r) {
      int lr  = iw + (lane >> 4) * 4 + r;
      int col = cb * 16 + (lane & 15);
      pbase[lr * 128 + hw * 64 + col] = acc[cb][r];
    }
  }
}

// ---------------------------------------------------------------------------
// K3: combine splits, normalize, add bias.
// ---------------------------------------------------------------------------
__global__ __launch_bounds__(256) void k3_finish(
    const float* __restrict__ part, const float* __restrict__ denp,
    const float* __restrict__ bias, float* __restrict__ out, const int S)
{
  const int idx = blockIdx.x * 256 + threadIdx.x;
  const int i  = idx >> 5;
  const int hc = (idx & 31) * 4;
  const int h  = hc >> 6;
  float4 s; s.x = s.y = s.z = s.w = 0.f;
  float d = 0.f;
  for (int sp = 0; sp < S; ++sp) {
    float4 v = *(const float4*)(part + ((size_t)sp * NN + i) * 128 + hc);
    s.x += v.x; s.y += v.y; s.z += v.z; s.w += v.w;
    d += denp[((size_t)sp * NN + i) * 2 + h];
  }
  const float sc = 1.f / (d + 0.001f);
  float4 bv = *(const float4*)(bias + hc);
  float4 o;
  o.x = s.x * sc + bv.x;
  o.y = s.y * sc + bv.y;
  o.z = s.z * sc + bv.z;
  o.w = s.w * sc + bv.w;
  *(float4*)(out + (size_t)i * 128 + hc) = o;
}

extern "C" void kernel_launch(void* const* d_in, const int* in_sizes, int n_in,
                              void* d_out, int out_size, void* d_ws, size_t ws_size,
                              hipStream_t stream) {
  const float* A    = (const float*)d_in[0];
  const float* X    = (const float*)d_in[1];
  const float* W    = (const float*)d_in[2];
  const float* attn = (const float*)d_in[3];
  const float* bias = (const float*)d_in[4];
  float* out = (float*)d_out;

  char* ws = (char*)d_ws;
  size_t off = 0;
  ushort_t* XpT = (ushort_t*)(ws + off); off += (size_t)128 * NN * sizeof(ushort_t);
  float* x0g = (float*)(ws + off); off += (size_t)NN * 2 * sizeof(float);
  float* x1g = (float*)(ws + off); off += (size_t)2 * NN * sizeof(float);

  int S = 4;
  while (S > 1) {
    size_t need = off + (size_t)S * NN * 2 * 4 + (size_t)S * NN * 128 * 4;
    if (need <= ws_size) break;
    S >>= 1;
  }
  float* denp = (float*)(ws + off); off += (size_t)S * NN * 2 * sizeof(float);
  float* part = (float*)(ws + off);
  const int KS = NN / S;

  k1_project<<<256, 256, 0, stream>>>(X, W, attn, XpT, x0g, x1g);
  k2_main<<<256 * S, 256, 0, stream>>>(A, XpT, x0g, x1g, part, denp, S, KS);
  k3_finish<<<1024, 256, 0, stream>>>(part, denp, bias, out, S);
}